// Round 1
// baseline (2069.622 us; speedup 1.0000x reference)
//
#include <hip/hip_runtime.h>

// SuperONN1d: per-channel fractional shift (lerp, zero pad) -> [x, x^2, x^3]
// channel expansion -> conv1d(384 -> 128, K=9, pad=4) + bias.
// B=16, Cin=Cout=128, L=8192, f32.
//
// Round 1: correctness-first fused f32 kernel.
//  - Each block: one (b, l-tile of 64, co-tile of 64).
//  - Stage shifted xs[128][72] (tile + K-1 halo) in LDS; positions outside
//    [0,L) are conv zero-padding -> 0.
//  - 256 threads as 16(tx=l) x 16(ty=co), 4x4 register micro-tile (stride 16).
//  - Horner: w1*s + w2*s^2 + w3*s^3 = s*(w1 + s*(w2 + s*w3)) -> 3 FMA/term.

#define B_    16
#define CIN   128
#define L_    8192
#define COUT  128
#define K_    9
#define PAD_  4

#define TL    64          // l-tile
#define TCO   64          // cout-tile
#define HALO  (K_ - 1)    // 8
#define XW    (TL + HALO) // 72 staged positions

__global__ __launch_bounds__(256) void superonn_f32_kernel(
    const float* __restrict__ x,       // [B, CIN, L]
    const float* __restrict__ w,       // [COUT, 3*CIN, K]
    const float* __restrict__ bias,    // [COUT]
    const float* __restrict__ shifts,  // [CIN, 2]
    float* __restrict__ out)           // [B, COUT, L]
{
    __shared__ float xs[CIN][XW];

    const int l0  = blockIdx.x * TL;
    const int co0 = blockIdx.y * TCO;
    const int b   = blockIdx.z;
    const int tid = threadIdx.x;

    // ---- stage channel-shifted x tile (with halo) into LDS ----
    const float* xb = x + (size_t)b * CIN * L_;
    for (int i = tid; i < CIN * XW; i += 256) {
        const int c  = i / XW;
        const int pp = i - c * XW;
        const int p  = l0 - PAD_ + pp;   // conv input position
        float val = 0.0f;
        if (p >= 0 && p < L_) {          // conv zero-padding outside [0,L)
            const float sh  = shifts[2 * c] * 4.0f;  // MAX_SHIFT = 4
            const float pos = (float)p + sh;
            const float f   = floorf(pos);
            const int   i0  = (int)f;
            const float w1  = pos - f;
            const float v0  = (i0     >= 0 && i0     < L_) ? xb[c * L_ + i0]     : 0.0f;
            const float v1  = (i0 + 1 >= 0 && i0 + 1 < L_) ? xb[c * L_ + i0 + 1] : 0.0f;
            val = v0 * (1.0f - w1) + v1 * w1;
        }
        xs[c][pp] = val;
    }
    __syncthreads();

    const int tx = tid & 15;   // l group
    const int ty = tid >> 4;   // co group

    float acc[4][4];
#pragma unroll
    for (int jc = 0; jc < 4; ++jc)
#pragma unroll
        for (int j = 0; j < 4; ++j) acc[jc][j] = 0.0f;

    // ---- main conv loop ----
    for (int ci = 0; ci < CIN; ++ci) {
#pragma unroll
        for (int k = 0; k < K_; ++k) {
            const float s0 = xs[ci][tx + 0  + k];
            const float s1 = xs[ci][tx + 16 + k];
            const float s2 = xs[ci][tx + 32 + k];
            const float s3 = xs[ci][tx + 48 + k];
#pragma unroll
            for (int jc = 0; jc < 4; ++jc) {
                const int co = co0 + ty + 16 * jc;
                const float* wp = w + ((size_t)co * (3 * CIN) + ci) * K_ + k;
                const float w1 = wp[0];
                const float w2 = wp[CIN * K_];        // q=2 block
                const float w3 = wp[2 * CIN * K_];    // q=3 block
                float t;
                t = fmaf(s0, w3, w2); t = fmaf(s0, t, w1); acc[jc][0] = fmaf(s0, t, acc[jc][0]);
                t = fmaf(s1, w3, w2); t = fmaf(s1, t, w1); acc[jc][1] = fmaf(s1, t, acc[jc][1]);
                t = fmaf(s2, w3, w2); t = fmaf(s2, t, w1); acc[jc][2] = fmaf(s2, t, acc[jc][2]);
                t = fmaf(s3, w3, w2); t = fmaf(s3, t, w1); acc[jc][3] = fmaf(s3, t, acc[jc][3]);
            }
        }
    }

    // ---- epilogue: + bias, store ----
#pragma unroll
    for (int jc = 0; jc < 4; ++jc) {
        const int co = co0 + ty + 16 * jc;
        const float bv = bias[co];
        float* op = out + ((size_t)b * COUT + co) * L_ + l0;
#pragma unroll
        for (int j = 0; j < 4; ++j) {
            op[tx + 16 * j] = acc[jc][j] + bv;
        }
    }
}

extern "C" void kernel_launch(void* const* d_in, const int* in_sizes, int n_in,
                              void* d_out, int out_size, void* d_ws, size_t ws_size,
                              hipStream_t stream) {
    const float* x      = (const float*)d_in[0];  // 16*128*8192
    const float* w      = (const float*)d_in[1];  // 128*384*9
    const float* bias   = (const float*)d_in[2];  // 128
    const float* shifts = (const float*)d_in[3];  // 128*2
    float* out = (float*)d_out;                   // 16*128*8192

    dim3 grid(L_ / TL, COUT / TCO, B_);           // 128 x 2 x 16 = 4096 blocks
    superonn_f32_kernel<<<grid, 256, 0, stream>>>(x, w, bias, shifts, out);
}

// Round 2
// 418.290 us; speedup vs baseline: 4.9478x; 4.9478x over previous
//
#include <hip/hip_runtime.h>

// SuperONN1d as implicit GEMM on bf16 MFMA.
//   out[b,co,l] = bias[co] + sum_{tap,q,ci} w[co,(q-1)*128+ci,tap] * xs[b,ci,l+tap-4]^q
// GEMM view: M=Cout=128, N=B*L, K=9*3*128=3456 (tap-major, then q, then ci).
//   A = weights (pre-converted bf16, k-major, in d_ws by prep kernel; streamed from L2)
//   B = shifted/powered inputs, staged per-block in LDS (bf16, k-major rows)
// One barrier per block (after staging); K-loop is barrier-free MFMA+ds_read+global_load.

#define B_    16
#define CIN   128
#define L_    8192
#define COUT  128
#define K_    9
#define PAD_  4
#define QMAX  3

#define TN    128                 // l-tile per block
#define XW    (TN + K_ - 1)       // 136 staged positions (tile + conv halo)
#define KQ    (QMAX * CIN)        // 384 = GEMM-K per tap
#define XROW  (KQ + 8)            // 392: +8 bf16 pad -> row stride 784 B (4-bank step)
#define KTOT  (K_ * KQ)           // 3456 = full GEMM-K

typedef __attribute__((ext_vector_type(8))) short bf16x8;  // 8 bf16 in 4 VGPRs
typedef __attribute__((ext_vector_type(4))) float f32x4;

__device__ __forceinline__ unsigned short f2bf(float v) {
    union { float f; unsigned u; } cv; cv.f = v;
    unsigned u = cv.u;
    return (unsigned short)((u + 0x7FFFu + ((u >> 16) & 1u)) >> 16);  // RNE
}

// ---- prep: w[co][q*128+ci][tap] (f32) -> wb[co][tap*384 + q*128 + ci] (bf16) ----
__global__ __launch_bounds__(256) void prep_weights(
    const float* __restrict__ w, unsigned short* __restrict__ wb)
{
    int i = blockIdx.x * 256 + threadIdx.x;
    if (i >= COUT * KTOT) return;
    int co  = i / KTOT;
    int r   = i - co * KTOT;
    int tap = r / KQ;
    int qc  = r - tap * KQ;                    // q*128 + ci
    wb[i] = f2bf(w[((size_t)co * KQ + qc) * K_ + tap]);
}

__global__ __launch_bounds__(512) void superonn_mfma(
    const float*          __restrict__ x,       // [B, CIN, L]
    const unsigned short* __restrict__ wb,      // [COUT, KTOT] bf16 k-major
    const float*          __restrict__ bias,    // [COUT]
    const float*          __restrict__ shifts,  // [CIN, 2]
    float*                __restrict__ out)     // [B, COUT, L]
{
    __shared__ unsigned short xq[XW * XROW];    // 136*392*2 = 106624 B

    const int l0  = blockIdx.x * TN;
    const int b   = blockIdx.y;
    const int tid = threadIdx.x;

    // ---- stage B-operand: xs, xs^2, xs^3 (f32 math, bf16 rounded) ----
    const float* xb = x + (size_t)b * CIN * L_;
    for (int it = 0; it < (CIN * XW) / 512; ++it) {   // 34 exact iterations
        const int idx = it * 512 + tid;
        const int ci  = idx / XW;
        const int pp  = idx - ci * XW;
        const int p   = l0 + pp - PAD_;               // conv input position
        float xs = 0.0f;
        if (p >= 0 && p < L_) {                       // conv zero padding
            const float sh  = shifts[2 * ci] * 4.0f;  // MAX_SHIFT
            const float pos = (float)p + sh;
            const float fl  = floorf(pos);
            const int   i0  = (int)fl;
            const float w1  = pos - fl;
            const float v0  = (i0     >= 0 && i0     < L_) ? xb[ci * L_ + i0]     : 0.0f;
            const float v1  = (i0 + 1 >= 0 && i0 + 1 < L_) ? xb[ci * L_ + i0 + 1] : 0.0f;
            xs = fmaf(w1, v1 - v0, v0);               // lerp
        }
        const float x2 = xs * xs;
        const float x3 = x2 * xs;
        unsigned short* row = &xq[pp * XROW];
        row[ci]            = f2bf(xs);
        row[CIN + ci]      = f2bf(x2);
        row[2 * CIN + ci]  = f2bf(x3);
    }
    __syncthreads();

    // ---- barrier-free MFMA K-loop ----
    const int lane = tid & 63;
    const int wv   = tid >> 6;          // 0..7
    const int wm   = wv & 3;            // co: frags {2wm, 2wm+1} -> rows wm*32..+31
    const int wn   = wv >> 2;           // l : frags {4wn..4wn+3} -> cols wn*64..+63
    const int l15  = lane & 15;
    const int quad = lane >> 4;

    f32x4 acc[2][4];
#pragma unroll
    for (int i = 0; i < 2; ++i)
#pragma unroll
        for (int j = 0; j < 4; ++j) acc[i][j] = (f32x4){0.f, 0.f, 0.f, 0.f};

    // A: row = wm*32 + i*16 + l15, col = tap*KQ + ks*32 + quad*8
    const unsigned short* aptr = wb + (size_t)(wm * 32 + l15) * KTOT + quad * 8;

    for (int tap = 0; tap < K_; ++tap) {
        const unsigned short* at = aptr + tap * KQ;
        // B: row pp = wn*64 + j*16 + l15 + tap, col = ks*32 + quad*8
        const unsigned short* bt = &xq[(wn * 64 + l15 + tap) * XROW + quad * 8];
#pragma unroll
        for (int ks = 0; ks < KQ / 32; ++ks) {        // 12
            const bf16x8 a0 = *(const bf16x8*)(at + ks * 32);
            const bf16x8 a1 = *(const bf16x8*)(at + 16 * KTOT + ks * 32);
#pragma unroll
            for (int j = 0; j < 4; ++j) {
                const bf16x8 bq = *(const bf16x8*)(bt + j * 16 * XROW + ks * 32);
                acc[0][j] = __builtin_amdgcn_mfma_f32_16x16x32_bf16(a0, bq, acc[0][j], 0, 0, 0);
                acc[1][j] = __builtin_amdgcn_mfma_f32_16x16x32_bf16(a1, bq, acc[1][j], 0, 0, 0);
            }
        }
    }

    // ---- epilogue: + bias, coalesced stores (lanes 0..15 = consecutive l) ----
#pragma unroll
    for (int i = 0; i < 2; ++i) {
#pragma unroll
        for (int j = 0; j < 4; ++j) {
            const int l = l0 + wn * 64 + j * 16 + l15;
#pragma unroll
            for (int r = 0; r < 4; ++r) {
                const int co = wm * 32 + i * 16 + quad * 4 + r;
                out[((size_t)b * COUT + co) * L_ + l] = acc[i][j][r] + bias[co];
            }
        }
    }
}

extern "C" void kernel_launch(void* const* d_in, const int* in_sizes, int n_in,
                              void* d_out, int out_size, void* d_ws, size_t ws_size,
                              hipStream_t stream) {
    const float* x      = (const float*)d_in[0];  // 16*128*8192
    const float* w      = (const float*)d_in[1];  // 128*384*9
    const float* bias   = (const float*)d_in[2];  // 128
    const float* shifts = (const float*)d_in[3];  // 128*2
    float* out = (float*)d_out;

    unsigned short* wb = (unsigned short*)d_ws;   // 128*3456*2 = 884736 B

    const int nw = COUT * KTOT;
    prep_weights<<<(nw + 255) / 256, 256, 0, stream>>>(w, wb);

    dim3 grid(L_ / TN, B_);                       // 64 x 16 = 1024 blocks
    superonn_mfma<<<grid, 512, 0, stream>>>(x, wb, bias, shifts, out);
}

// Round 3
// 376.171 us; speedup vs baseline: 5.5018x; 1.1120x over previous
//
#include <hip/hip_runtime.h>

// SuperONN1d as implicit GEMM on bf16 MFMA (32x32x16).
//   out[b,co,l] = bias[co] + sum_{tap,q,ci} w[co,q*128+ci,tap] * xs[b,ci,l+tap-4]^(q+1)
// GEMM: M=Cout=128, N=B*L, K=9*3*128=3456 (k = tap*384 + q*128 + ci).
// Per block (TN=128 l-tile): B staged in LDS (bf16, odd-dword row stride -> no
// bank conflicts); A pre-swizzled to MFMA fragment order in d_ws (coalesced
// 1024B wave loads from L2). 16 waves = 2(co64) x 4(l32) x 2(K-split),
// K-halves reduced through LDS. 4 waves/SIMD for latency hiding.

#define B_    16
#define CIN   128
#define L_    8192
#define COUT  128
#define K_    9
#define PAD_  4
#define QMAX  3

#define TN    128
#define XW    (TN + K_ - 1)       // 136 staged positions
#define KQ    (QMAX * CIN)        // 384 GEMM-K per tap
#define XROW  (KQ + 2)            // 386 shorts = 772 B = 193 dwords (odd -> conflict-free)
#define KTOT  (K_ * KQ)           // 3456
#define NKT   (KTOT / 16)         // 216 K16-chunks
#define RSTR  132                 // f32 reduction scratch l-stride

typedef __attribute__((ext_vector_type(8)))  short bf16x8;   // 4 VGPRs
typedef __attribute__((ext_vector_type(16))) float f32x16;   // 32x32 accumulator

__device__ __forceinline__ unsigned short f2bf(float v) {
    union { float f; unsigned u; } cv; cv.f = v;
    unsigned u = cv.u;
    return (unsigned short)((u + 0x7FFFu + ((u >> 16) & 1u)) >> 16);  // RNE
}

// ---- prep: w[co][qc][tap] (f32) -> A-fragment order (bf16) ----
// Layout: [g(co64)][kt(216)][sub(2)][lane(64)][8], where within a frag
//   co = g*64 + sub*32 + (lane&31), k = kt*16 + (lane>>5)*8 + i.
__global__ __launch_bounds__(256) void prep_weights(
    const float* __restrict__ w, unsigned short* __restrict__ wb)
{
    int idx = blockIdx.x * 256 + threadIdx.x;
    if (idx >= COUT * KTOT) return;
    const int g    = idx / (NKT * 1024);        // 221184 per co64-group
    const int r    = idx - g * (NKT * 1024);
    const int kt   = r >> 10;
    const int r2   = r & 1023;
    const int sub  = r2 >> 9;
    const int lane = (r2 >> 3) & 63;
    const int i    = r2 & 7;
    const int co   = g * 64 + sub * 32 + (lane & 31);
    const int k    = kt * 16 + (lane >> 5) * 8 + i;
    const int tap  = k / KQ;
    const int qc   = k - tap * KQ;
    wb[idx] = f2bf(w[((size_t)co * KQ + qc) * K_ + tap]);
}

__global__ __launch_bounds__(1024, 4) void superonn_mfma(
    const float*          __restrict__ x,       // [B, CIN, L]
    const unsigned short* __restrict__ wb,      // A frags, bf16
    const float*          __restrict__ bias,    // [COUT]
    const float*          __restrict__ shifts,  // [CIN, 2]
    float*                __restrict__ out)     // [B, COUT, L]
{
    __shared__ __align__(16) unsigned short xq[XW * XROW];  // 104,992 B

    const int l0  = blockIdx.x * TN;
    const int b   = blockIdx.y;
    const int tid = threadIdx.x;

    // ---- stage B: shift-lerp + powers, f32 math -> bf16 ----
    const float* xb = x + (size_t)b * CIN * L_;
    for (int it = 0; it < (CIN * XW) / 1024; ++it) {   // 17 exact
        const int idx = it * 1024 + tid;
        const int ci  = idx / XW;
        const int pp  = idx - ci * XW;
        const int p   = l0 + pp - PAD_;
        float xs = 0.0f;
        if (p >= 0 && p < L_) {                        // conv zero padding
            const float sh  = shifts[2 * ci] * 4.0f;   // MAX_SHIFT
            const float pos = (float)p + sh;
            const float fl  = floorf(pos);
            const int   i0  = (int)fl;
            const float w1  = pos - fl;
            const float v0  = (i0     >= 0 && i0     < L_) ? xb[ci * L_ + i0]     : 0.0f;
            const float v1  = (i0 + 1 >= 0 && i0 + 1 < L_) ? xb[ci * L_ + i0 + 1] : 0.0f;
            xs = fmaf(w1, v1 - v0, v0);
        }
        const float x2 = xs * xs;
        const float x3 = x2 * xs;
        unsigned short* row = &xq[pp * XROW];
        row[ci]           = f2bf(xs);
        row[CIN + ci]     = f2bf(x2);
        row[2 * CIN + ci] = f2bf(x3);
    }
    __syncthreads();

    // ---- wave decomposition: wm(co64) x wl(l32) x wk(K-half) ----
    const int lane = tid & 63;
    const int wv   = tid >> 6;
    const int wk   = wv & 1;
    const int wl   = (wv >> 1) & 3;
    const int wm   = wv >> 3;
    const int h    = lane >> 5;
    const int n5   = lane & 31;

    f32x16 acc0 = {};
    f32x16 acc1 = {};

    // A: frag (wm, kt=tap*24+2*jj+wk, sub), lane-contiguous 1024B chunks
    const unsigned short* abase = wb + ((size_t)wm * NKT + wk) * 1024 + lane * 8;
    // B: row = wl*32 + n5 + tap, col = (2*jj+wk)*16 + h*8
    const unsigned short* brow0 = &xq[(wl * 32 + n5) * XROW + h * 8 + wk * 16];

    for (int tap = 0; tap < K_; ++tap) {
        const unsigned short* at = abase + (size_t)tap * 24 * 1024;
        const unsigned short* bt = brow0 + tap * XROW;
#pragma unroll
        for (int jj = 0; jj < 12; ++jj) {
            const bf16x8 a0 = *(const bf16x8*)(at);
            const bf16x8 a1 = *(const bf16x8*)(at + 512);
            const bf16x8 bq = *(const bf16x8*)(bt);
            acc0 = __builtin_amdgcn_mfma_f32_32x32x16_bf16(a0, bq, acc0, 0, 0, 0);
            acc1 = __builtin_amdgcn_mfma_f32_32x32x16_bf16(a1, bq, acc1, 0, 0, 0);
            at += 2048;   // kt += 2 (2 subs x 512)
            bt += 32;     // kq0 += 32
        }
    }

    // ---- K-split reduction through LDS, + bias, store ----
    __syncthreads();                    // xq no longer needed as bf16
    float* red = (float*)xq;            // [128][RSTR] = 67,584 B, fits
    const int lloc = wl * 32 + n5;

    if (wk) {
#pragma unroll
        for (int r = 0; r < 16; ++r) {
            const int row = (r & 3) + 8 * (r >> 2) + 4 * h;   // C/D row map (32x32)
            red[(wm * 64 + row)      * RSTR + lloc] = acc0[r];
            red[(wm * 64 + 32 + row) * RSTR + lloc] = acc1[r];
        }
    }
    __syncthreads();
    if (!wk) {
#pragma unroll
        for (int r = 0; r < 16; ++r) {
            const int row = (r & 3) + 8 * (r >> 2) + 4 * h;
            const int co0 = wm * 64 + row;
            const int co1 = co0 + 32;
            const float v0 = acc0[r] + red[co0 * RSTR + lloc] + bias[co0];
            const float v1 = acc1[r] + red[co1 * RSTR + lloc] + bias[co1];
            out[((size_t)b * COUT + co0) * L_ + l0 + lloc] = v0;
            out[((size_t)b * COUT + co1) * L_ + l0 + lloc] = v1;
        }
    }
}

extern "C" void kernel_launch(void* const* d_in, const int* in_sizes, int n_in,
                              void* d_out, int out_size, void* d_ws, size_t ws_size,
                              hipStream_t stream) {
    const float* x      = (const float*)d_in[0];  // 16*128*8192
    const float* w      = (const float*)d_in[1];  // 128*384*9
    const float* bias   = (const float*)d_in[2];  // 128
    const float* shifts = (const float*)d_in[3];  // 128*2
    float* out = (float*)d_out;

    unsigned short* wb = (unsigned short*)d_ws;   // 128*3456*2 = 884,736 B

    const int nw = COUT * KTOT;                   // 442,368
    prep_weights<<<(nw + 255) / 256, 256, 0, stream>>>(w, wb);

    dim3 grid(L_ / TN, B_);                       // 64 x 16 = 1024 blocks
    superonn_mfma<<<grid, 1024, 0, stream>>>(x, wb, bias, shifts, out);
}